// Round 19
// baseline (279.524 us; speedup 1.0000x reference)
//
#include <hip/hip_runtime.h>

#define ND 4
#define ED 128
#define KCODES 4096
#define NTOK 16384          // B*S
#define HID 512
#define NTOT (ND*ED*NTOK)   // 8388608

#define MARGIN 2.0e-3f
#define FLAG_CAP 16384

typedef __attribute__((ext_vector_type(8))) short short8v;
typedef __attribute__((ext_vector_type(4))) float float4v;

#define GLDS16(g, l) __builtin_amdgcn_global_load_lds( \
    (const __attribute__((address_space(1))) unsigned int*)(g), \
    (__attribute__((address_space(3))) unsigned int*)(l), 16, 0, 0)

__device__ __forceinline__ unsigned short bf16h(float x) {
    unsigned u = __float_as_uint(x);
    return (unsigned short)((u + 0x7fffu + ((u >> 16) & 1u)) >> 16);
}
__device__ __forceinline__ float bf16f(unsigned short h) {
    return __uint_as_float(((unsigned)h) << 16);
}

// Fused: exact e2 (serial asc-e mul/add, bit-matches ref) + B hi/lo split into
// one linear 8KB record per (d,16-code tile) == the LDS image GLDS will build.
// Record layout (bytes): arr(2)*4096 + code(16)*256 + kpos(16)*16 + j(8)*2,
// kpos = (logical k-octet) ^ code  (bank swizzle baked in).
__global__ __launch_bounds__(256) void e2split_kernel(const float* __restrict__ emb,
        float* __restrict__ e2g, unsigned short* __restrict__ bfrag,
        int* __restrict__ flag_cnt) {
    __shared__ float Tf[128][17];
    const int tile = blockIdx.x;      // 16-code tile
    const int d    = blockIdx.y;
    const int tid  = threadIdx.x;
    const int k0   = tile * 16;
    if (tile == 0 && d == 0 && tid == 0) *flag_cnt = 0;
    {
        int e = tid >> 1, half = tid & 1;
        const float* src = emb + ((size_t)d * ED + e) * KCODES + k0 + half * 8;
        float4 v0 = *(const float4*)(src);
        float4 v1 = *(const float4*)(src + 4);
        float* dst = &Tf[e][half * 8];
        dst[0] = v0.x; dst[1] = v0.y; dst[2] = v0.z; dst[3] = v0.w;
        dst[4] = v1.x; dst[5] = v1.y; dst[6] = v1.z; dst[7] = v1.w;
    }
    __syncthreads();
    if (tid < 16) {
        float s = 0.f;
        for (int e = 0; e < ED; ++e) {
            float v = Tf[e][tid];
            s = __fadd_rn(s, __fmul_rn(v, v));
        }
        e2g[d * KCODES + k0 + tid] = s;
    }
    #pragma unroll
    for (int q = 0; q < 2; ++q) {
        int c    = q * 256 + tid;          // 0..511 chunks of 16B
        int arr  = c >> 8;
        int rem  = c & 255;
        int code = rem >> 4;
        int kpos = rem & 15;
        int e0   = (kpos ^ code) * 8;
        short8v v;
        #pragma unroll
        for (int j = 0; j < 8; ++j) {
            float x = Tf[e0 + j][code];
            unsigned short hb = bf16h(x);
            v[j] = arr ? (short)bf16h(x - bf16f(hb)) : (short)hb;
        }
        size_t idx = ((size_t)(d * 256 + tile)) * 4096 + arr * 2048 + code * 128 + kpos * 8;
        *(short8v*)(bfrag + idx) = v;
    }
}

// MFMA bf16x3 argmin, K-split across blocks: block = (d, half, 128 tokens),
// 4 waves x 32 tok, 2048 codes (128 tiles). Counted-vmcnt pipeline, 4 blocks/CU.
// Per-token (key, m2) partials to global; merge kernel combines halves.
__global__ __launch_bounds__(256, 2)
void argmin_mfma_kernel(const float* __restrict__ in,
        const unsigned short* __restrict__ bfrag, const float* __restrict__ e2g,
        unsigned long long* __restrict__ pk, unsigned* __restrict__ pm2) {
    __shared__ __align__(16) char LB[40960];   // 4 x 8KB staging + 8KB e2p

    // XCD-aware decode: XCD r8 owns combo (d = r8>>1, h = r8&1)
    const int l   = blockIdx.x;           // 0..1023
    const int r8  = l & 7;
    const int d   = r8 >> 1;
    const int h   = r8 & 1;
    const int tI  = l >> 3;               // 0..127
    const int t0  = tI * 128;

    const int tid  = threadIdx.x;
    const int w    = tid >> 6;
    const int lane = tid & 63;
    const int l15  = lane & 15;
    const int lk8  = lane >> 4;     // 0..3

    float* e2p = (float*)(LB + 32768);     // this half's 2048 biased e2
    #pragma unroll
    for (int i = 0; i < 8; ++i) {
        int idx = i * 256 + tid;
        e2p[idx] = e2g[d * KCODES + h * 2048 + idx] + 512.0f;   // bias -> positive
    }

    // A fragments: rows t0 + w*32 + rt*16 + l15, e = ks*32 + lk8*8 + j
    short8v ahf[2][4], alf[2][4];
    #pragma unroll
    for (int rt = 0; rt < 2; ++rt) {
        const float* ap = in + (size_t)(t0 + w * 32 + rt * 16 + l15) * HID + d * ED + lk8 * 8;
        #pragma unroll
        for (int ks = 0; ks < 4; ++ks) {
            float4 v0 = *(const float4*)(ap + ks * 32);
            float4 v1 = *(const float4*)(ap + ks * 32 + 4);
            float vv[8] = {v0.x, v0.y, v0.z, v0.w, v1.x, v1.y, v1.z, v1.w};
            short8v hv, lv;
            #pragma unroll
            for (int j = 0; j < 8; ++j) {
                unsigned short hb = bf16h(vv[j]);
                hv[j] = (short)hb;
                lv[j] = (short)bf16h(vv[j] - bf16f(hb));
            }
            ahf[rt][ks] = hv; alf[rt][ks] = lv;
        }
    }

    // per-lane frag byte-offsets within a buffer (swizzle-matched to bsplit)
    int fo[4];
    #pragma unroll
    for (int ks = 0; ks < 4; ++ks)
        fo[ks] = l15 * 256 + (((ks * 4 + lk8) ^ l15) * 16);

    // staging source: this half's 128 tile records
    const char* sb = (const char*)bfrag + ((size_t)(d * 256 + h * 128)) * 8192 + tid * 16;

    // prologue: stage tiles 0,1
    #pragma unroll
    for (int t = 0; t < 2; ++t) {
        GLDS16(sb + t * 8192,        LB + t * 8192 + w * 1024);
        GLDS16(sb + t * 8192 + 4096, LB + t * 8192 + 4096 + w * 1024);
    }
    __syncthreads();

    unsigned m1[2][4], m2[2][4];
    int bk[2][4];
    #pragma unroll
    for (int rt = 0; rt < 2; ++rt)
        #pragma unroll
        for (int r = 0; r < 4; ++r) { m1[rt][r] = 0xFFFFFFFFu; m2[rt][r] = 0xFFFFFFFFu; bk[rt][r] = 0; }

    #pragma unroll 4
    for (int s = 0; s < 128; ++s) {
        if (s < 126) {      // stage tile s+2 (stays in flight across barriers)
            const char* sp = sb + (size_t)(s + 2) * 8192;
            char* dp = LB + ((s + 2) & 3) * 8192 + w * 1024;
            GLDS16(sp,        dp);
            GLDS16(sp + 4096, dp + 4096);
        }
        const char* cur = LB + (s & 3) * 8192;
        const float e2v = e2p[s * 16 + l15];

        float4v aP[2] = {{0,0,0,0},{0,0,0,0}};
        float4v aQ[2] = {{0,0,0,0},{0,0,0,0}};
        __builtin_amdgcn_s_setprio(1);
        #pragma unroll
        for (int ks = 0; ks < 4; ++ks) {
            short8v bh = *(const short8v*)(cur + fo[ks]);
            short8v bl = *(const short8v*)(cur + 4096 + fo[ks]);
            aP[0] = __builtin_amdgcn_mfma_f32_16x16x32_bf16(ahf[0][ks], bh, aP[0], 0, 0, 0);
            aP[1] = __builtin_amdgcn_mfma_f32_16x16x32_bf16(ahf[1][ks], bh, aP[1], 0, 0, 0);
            aP[0] = __builtin_amdgcn_mfma_f32_16x16x32_bf16(alf[0][ks], bh, aP[0], 0, 0, 0);
            aP[1] = __builtin_amdgcn_mfma_f32_16x16x32_bf16(alf[1][ks], bh, aP[1], 0, 0, 0);
            aQ[0] = __builtin_amdgcn_mfma_f32_16x16x32_bf16(ahf[0][ks], bl, aQ[0], 0, 0, 0);
            aQ[1] = __builtin_amdgcn_mfma_f32_16x16x32_bf16(ahf[1][ks], bl, aQ[1], 0, 0, 0);
        }
        __builtin_amdgcn_s_setprio(0);
        #pragma unroll
        for (int rt = 0; rt < 2; ++rt) {
            #pragma unroll
            for (int r = 0; r < 4; ++r) {
                float cs = aP[rt][r] + aQ[rt][r];
                float dv = __fmaf_rn(-2.0f, cs, e2v);          // positive (bias)
                unsigned kk = __float_as_uint(dv);
                unsigned mo = m1[rt][r];
                unsigned mx = mo > kk ? mo : kk;
                m2[rt][r] = m2[rt][r] < mx ? m2[rt][r] : mx;
                if (kk < mo) { bk[rt][r] = s; m1[rt][r] = kk; }
            }
        }
        if (s < 126)        asm volatile("s_waitcnt vmcnt(2)" ::: "memory");
        else if (s == 126)  asm volatile("s_waitcnt vmcnt(0)" ::: "memory");
        __builtin_amdgcn_s_barrier();
    }

    // exact u64 butterfly over the 16 code-lanes; low bits carry code (tiebreak)
    #pragma unroll
    for (int rt = 0; rt < 2; ++rt) {
        #pragma unroll
        for (int r = 0; r < 4; ++r) {
            unsigned long long key = ((unsigned long long)m1[rt][r] << 32) |
                                     (unsigned)(h * 2048 + bk[rt][r] * 16 + l15);
            unsigned mm2 = m2[rt][r];
            #pragma unroll
            for (int m = 1; m <= 8; m <<= 1) {
                unsigned long long ok = __shfl_xor(key, m, 64);
                unsigned om = __shfl_xor(mm2, m, 64);
                unsigned loser = (ok < key) ? (unsigned)(key >> 32) : (unsigned)(ok >> 32);
                key = ok < key ? ok : key;
                unsigned t2 = om < loser ? om : loser;
                mm2 = mm2 < t2 ? mm2 : t2;
            }
            if (l15 == 0) {
                int tok = d * NTOK + t0 + w * 32 + rt * 16 + lk8 * 4 + r;
                pk[(size_t)h * 65536 + tok] = key;
                pm2[(size_t)h * 65536 + tok] = mm2;
            }
        }
    }
}

// Merge the two code-halves per token: exact u64 first-min + gap flagging.
__global__ __launch_bounds__(256) void merge_kernel(
        const unsigned long long* __restrict__ pk, const unsigned* __restrict__ pm2,
        int* __restrict__ lat, int* __restrict__ flag_cnt, int* __restrict__ flag_list) {
    int tok = blockIdx.x * 256 + threadIdx.x;   // 0..65535 == d*NTOK + t
    unsigned long long ka = pk[tok], kb = pk[65536 + tok];
    unsigned m2a = pm2[tok], m2b = pm2[65536 + tok];
    bool aw = ka < kb;
    unsigned long long kw = aw ? ka : kb;
    unsigned loser1 = (unsigned)((aw ? kb : ka) >> 32);
    unsigned m2w = aw ? m2a : m2b;
    unsigned B2 = m2w < loser1 ? m2w : loser1;
    lat[tok] = (int)(kw & 0xFFFFu);
    float gap = __uint_as_float(B2) - __uint_as_float((unsigned)(kw >> 32));
    if (gap < MARGIN) {
        int slot = atomicAdd(flag_cnt, 1);
        if (slot < FLAG_CAP) flag_list[slot] = tok;
    }
}

// Exact repair, bit-matching verified ref semantics (x2 computed in-kernel).
__global__ __launch_bounds__(256) void repair_kernel(const float* __restrict__ in,
        const float* __restrict__ emb, const float* __restrict__ e2g,
        const int* __restrict__ flag_cnt, const int* __restrict__ flag_list,
        int* __restrict__ lat) {
    __shared__ float xs[ED];
    __shared__ float rd[256];
    __shared__ int   rk[256];
    int n = *flag_cnt;
    if (n > FLAG_CAP) n = FLAG_CAP;
    for (int idx = blockIdx.x; idx < n; idx += gridDim.x) {
        int tok = flag_list[idx];
        int d = tok >> 14;               // tok = d*NTOK + t
        int t = tok & (NTOK - 1);
        __syncthreads();
        if (threadIdx.x < ED) xs[threadIdx.x] = in[(size_t)t * HID + d * ED + threadIdx.x];
        __syncthreads();
        float x2v = 0.f;                 // strict serial, matches ref
        for (int e = 0; e < ED; ++e) x2v = __fadd_rn(x2v, __fmul_rn(xs[e], xs[e]));
        const float* __restrict__ embd = emb + (size_t)d * ED * KCODES;
        float bd = 3.0e38f; int bkk = 0;
        for (int j = 0; j < 16; ++j) {
            int k = threadIdx.x + j * 256;      // ascending k per thread
            float acc = 0.f;
            #pragma unroll 16
            for (int e = 0; e < ED; ++e)
                acc = __fmaf_rn(xs[e], embd[(size_t)e * KCODES + k], acc);
            float dist = __fsub_rn(__fadd_rn(x2v, e2g[d * KCODES + k]),
                                   __fmul_rn(2.0f, acc));
            if (dist < bd) { bd = dist; bkk = k; }
        }
        rd[threadIdx.x] = bd; rk[threadIdx.x] = bkk;
        __syncthreads();
        for (int w = 128; w > 0; w >>= 1) {
            if (threadIdx.x < w) {
                float od = rd[threadIdx.x + w]; int ok = rk[threadIdx.x + w];
                if (od < rd[threadIdx.x] || (od == rd[threadIdx.x] && ok < rk[threadIdx.x])) {
                    rd[threadIdx.x] = od; rk[threadIdx.x] = ok;
                }
            }
            __syncthreads();
        }
        if (threadIdx.x == 0) lat[tok] = rk[0];
    }
}

// out[n] = fl(fl(x + e) - x), n = (d,e,t); per-block partials of (x - e)^2
__global__ __launch_bounds__(256) void gather_kernel(const float* __restrict__ in,
        const float* __restrict__ emb, const int* __restrict__ lat,
        float* __restrict__ out, float* __restrict__ partial) {
    int tid  = threadIdx.x;
    int base = blockIdx.x * 1024 + tid * 4;
    int d = base >> 21;
    int e = (base >> 14) & 127;
    int t = base & (NTOK - 1);
    const int4 kk = *(const int4*)(lat + d * NTOK + t);
    const float* __restrict__ row = emb + ((size_t)(d * ED + e)) * KCODES;
    float enc[4];
    enc[0] = row[kk.x]; enc[1] = row[kk.y]; enc[2] = row[kk.z]; enc[3] = row[kk.w];
    const float4 x = *(const float4*)(in + base);
    const float xv[4] = {x.x, x.y, x.z, x.w};
    float4 ov; float* o = (float*)&ov;
    float s = 0.f;
    #pragma unroll
    for (int i = 0; i < 4; ++i) {
        o[i] = __fsub_rn(__fadd_rn(xv[i], enc[i]), xv[i]);
        float df = xv[i] - enc[i];
        s = __fmaf_rn(df, df, s);
    }
    *(float4*)(out + base) = ov;
    #pragma unroll
    for (int off = 32; off > 0; off >>= 1) s += __shfl_down(s, off, 64);
    __shared__ float wsum[4];
    if ((tid & 63) == 0) wsum[tid >> 6] = s;
    __syncthreads();
    if (tid == 0) partial[blockIdx.x] = wsum[0] + wsum[1] + wsum[2] + wsum[3];
}

__global__ __launch_bounds__(256) void finalize_kernel(const float* __restrict__ partial,
                                                       float* __restrict__ out_tail) {
    __shared__ double sh[256];
    double s = 0.0;
    for (int i = threadIdx.x; i < 8192; i += 256) s += (double)partial[i];
    sh[threadIdx.x] = s;
    __syncthreads();
    for (int w = 128; w > 0; w >>= 1) {
        if (threadIdx.x < w) sh[threadIdx.x] += sh[threadIdx.x + w];
        __syncthreads();
    }
    if (threadIdx.x == 0) {
        double mean = sh[0] / (double)NTOT;
        out_tail[0] = (float)(0.25 * mean);   // loss
        out_tail[1] = (float)mean;            // commit_loss
        ((int*)out_tail)[2] = 0;              // kl (int32 0 == fp32 0.0 bits)
    }
}

extern "C" void kernel_launch(void* const* d_in, const int* in_sizes, int n_in,
                              void* d_out, int out_size, void* d_ws, size_t ws_size,
                              hipStream_t stream) {
    const float* in  = (const float*)d_in[0];
    const float* emb = (const float*)d_in[1];
    float* out = (float*)d_out;
    char* ws = (char*)d_ws;

    int*   lat       = (int*)ws;                          // 256 KB
    float* e2g       = (float*)(ws + 262144);             // 64 KB
    float* partial   = (float*)(ws + 327680);             // 32 KB
    int*   flag_cnt  = (int*)(ws + 360448);               // 4 B
    int*   flag_list = (int*)(ws + 360452);               // 64 KB
    unsigned long long* pk  = (unsigned long long*)(ws + 458752);   // 1 MB
    unsigned*           pm2 = (unsigned*)(ws + 1572864);            // 512 KB
    unsigned short* bfrag = (unsigned short*)(ws + 2097152);        // 8 MB

    hipLaunchKernelGGL(e2split_kernel, dim3(256, 4), dim3(256), 0, stream,
                       emb, e2g, bfrag, flag_cnt);
    hipLaunchKernelGGL(argmin_mfma_kernel, dim3(1024), dim3(256), 0, stream,
                       in, bfrag, e2g, pk, pm2);
    hipLaunchKernelGGL(merge_kernel, dim3(256), dim3(256), 0, stream,
                       pk, pm2, lat, flag_cnt, flag_list);
    hipLaunchKernelGGL(repair_kernel, dim3(64), dim3(256), 0, stream,
                       in, emb, e2g, flag_cnt, flag_list, lat);
    hipLaunchKernelGGL(gather_kernel, dim3(NTOT / 1024), dim3(256), 0, stream,
                       in, emb, lat, out, partial);
    hipLaunchKernelGGL(finalize_kernel, dim3(1), dim3(256), 0, stream, partial, out + NTOT);
}

// Round 20
// 273.831 us; speedup vs baseline: 1.0208x; 1.0208x over previous
//
#include <hip/hip_runtime.h>

#define ND 4
#define ED 128
#define KCODES 4096
#define NTOK 16384          // B*S
#define HID 512
#define NTOT (ND*ED*NTOK)   // 8388608

#define MARGIN 2.0e-3f
#define FLAG_CAP 16384

typedef __attribute__((ext_vector_type(8))) short short8v;
typedef __attribute__((ext_vector_type(4))) float float4v;

#define GLDS16(g, l) __builtin_amdgcn_global_load_lds( \
    (const __attribute__((address_space(1))) unsigned int*)(g), \
    (__attribute__((address_space(3))) unsigned int*)(l), 16, 0, 0)

__device__ __forceinline__ unsigned short bf16h(float x) {
    unsigned u = __float_as_uint(x);
    return (unsigned short)((u + 0x7fffu + ((u >> 16) & 1u)) >> 16);
}
__device__ __forceinline__ float bf16f(unsigned short h) {
    return __uint_as_float(((unsigned)h) << 16);
}

// Fused: exact e2 (serial asc-e mul/add, bit-matches ref) + B hi/lo split into
// one linear 8KB record per (d,16-code tile) == the LDS image GLDS will build.
__global__ __launch_bounds__(256) void e2split_kernel(const float* __restrict__ emb,
        float* __restrict__ e2g, unsigned short* __restrict__ bfrag,
        int* __restrict__ flag_cnt) {
    __shared__ float Tf[128][17];
    const int tile = blockIdx.x;      // 16-code tile
    const int d    = blockIdx.y;
    const int tid  = threadIdx.x;
    const int k0   = tile * 16;
    if (tile == 0 && d == 0 && tid == 0) *flag_cnt = 0;
    {
        int e = tid >> 1, half = tid & 1;
        const float* src = emb + ((size_t)d * ED + e) * KCODES + k0 + half * 8;
        float4 v0 = *(const float4*)(src);
        float4 v1 = *(const float4*)(src + 4);
        float* dst = &Tf[e][half * 8];
        dst[0] = v0.x; dst[1] = v0.y; dst[2] = v0.z; dst[3] = v0.w;
        dst[4] = v1.x; dst[5] = v1.y; dst[6] = v1.z; dst[7] = v1.w;
    }
    __syncthreads();
    if (tid < 16) {
        float s = 0.f;
        for (int e = 0; e < ED; ++e) {
            float v = Tf[e][tid];
            s = __fadd_rn(s, __fmul_rn(v, v));
        }
        e2g[d * KCODES + k0 + tid] = s;
    }
    #pragma unroll
    for (int q = 0; q < 2; ++q) {
        int c    = q * 256 + tid;          // 0..511 chunks of 16B
        int arr  = c >> 8;
        int rem  = c & 255;
        int code = rem >> 4;
        int kpos = rem & 15;
        int e0   = (kpos ^ code) * 8;
        short8v v;
        #pragma unroll
        for (int j = 0; j < 8; ++j) {
            float x = Tf[e0 + j][code];
            unsigned short hb = bf16h(x);
            v[j] = arr ? (short)bf16h(x - bf16f(hb)) : (short)hb;
        }
        size_t idx = ((size_t)(d * 256 + tile)) * 4096 + arr * 2048 + code * 128 + kpos * 8;
        *(short8v*)(bfrag + idx) = v;
    }
}

// MFMA bf16x3 argmin, K-split across blocks + B-fragment REGISTER RING:
// per ks-step: 6 MFMAs from ring slot, then ds_read NEXT tile's ks-frags into
// the same slot -> MFMA cluster has no lgkm dep on this iter's reads (per-wave
// LDS/MFMA overlap). Stage j+3, vmcnt(2) => tiles <= j+2 resident => reading
// tile j+1 during iter j is always safe. 4 LDS bufs + e2p = 40KB.
__global__ __launch_bounds__(256, 2)
void argmin_mfma_kernel(const float* __restrict__ in,
        const unsigned short* __restrict__ bfrag, const float* __restrict__ e2g,
        unsigned long long* __restrict__ pk, unsigned* __restrict__ pm2) {
    __shared__ __align__(16) char LB[40960];   // 4 x 8KB staging + 8KB e2p

    // XCD-aware decode: XCD r8 owns combo (d = r8>>1, h = r8&1)
    const int l   = blockIdx.x;           // 0..1023
    const int r8  = l & 7;
    const int d   = r8 >> 1;
    const int h   = r8 & 1;
    const int tI  = l >> 3;               // 0..127
    const int t0  = tI * 128;

    const int tid  = threadIdx.x;
    const int w    = tid >> 6;
    const int lane = tid & 63;
    const int l15  = lane & 15;
    const int lk8  = lane >> 4;     // 0..3

    float* e2p = (float*)(LB + 32768);     // this half's 2048 biased e2
    #pragma unroll
    for (int i = 0; i < 8; ++i) {
        int idx = i * 256 + tid;
        e2p[idx] = e2g[d * KCODES + h * 2048 + idx] + 512.0f;   // bias -> positive
    }

    // A fragments: rows t0 + w*32 + rt*16 + l15, e = ks*32 + lk8*8 + j
    short8v ahf[2][4], alf[2][4];
    #pragma unroll
    for (int rt = 0; rt < 2; ++rt) {
        const float* ap = in + (size_t)(t0 + w * 32 + rt * 16 + l15) * HID + d * ED + lk8 * 8;
        #pragma unroll
        for (int ks = 0; ks < 4; ++ks) {
            float4 v0 = *(const float4*)(ap + ks * 32);
            float4 v1 = *(const float4*)(ap + ks * 32 + 4);
            float vv[8] = {v0.x, v0.y, v0.z, v0.w, v1.x, v1.y, v1.z, v1.w};
            short8v hv, lv;
            #pragma unroll
            for (int j = 0; j < 8; ++j) {
                unsigned short hb = bf16h(vv[j]);
                hv[j] = (short)hb;
                lv[j] = (short)bf16h(vv[j] - bf16f(hb));
            }
            ahf[rt][ks] = hv; alf[rt][ks] = lv;
        }
    }

    // per-lane frag byte-offsets within a buffer (swizzle-matched to bsplit)
    int fo[4];
    #pragma unroll
    for (int ks = 0; ks < 4; ++ks)
        fo[ks] = l15 * 256 + (((ks * 4 + lk8) ^ l15) * 16);

    // staging source: this half's 128 tile records
    const char* sb = (const char*)bfrag + ((size_t)(d * 256 + h * 128)) * 8192 + tid * 16;

    // prologue: stage tiles 0,1,2; vmcnt(2) -> tiles 0,1 resident
    #pragma unroll
    for (int t = 0; t < 3; ++t) {
        GLDS16(sb + t * 8192,        LB + t * 8192 + w * 1024);
        GLDS16(sb + t * 8192 + 4096, LB + t * 8192 + 4096 + w * 1024);
    }
    asm volatile("s_waitcnt vmcnt(2)" ::: "memory");
    __syncthreads();

    // preload ring with tile 0's fragments
    short8v rbh[4], rbl[4];
    #pragma unroll
    for (int ks = 0; ks < 4; ++ks) {
        rbh[ks] = *(const short8v*)(LB + fo[ks]);
        rbl[ks] = *(const short8v*)(LB + 4096 + fo[ks]);
    }

    unsigned m1[2][4], m2[2][4];
    int bk[2][4];
    #pragma unroll
    for (int rt = 0; rt < 2; ++rt)
        #pragma unroll
        for (int r = 0; r < 4; ++r) { m1[rt][r] = 0xFFFFFFFFu; m2[rt][r] = 0xFFFFFFFFu; bk[rt][r] = 0; }

    #pragma unroll 4
    for (int j = 0; j < 128; ++j) {
        if (j < 125) {      // stage tile j+3 (in flight across barriers)
            const char* sp = sb + (size_t)(j + 3) * 8192;
            char* dp = LB + ((j + 3) & 3) * 8192 + w * 1024;
            GLDS16(sp,        dp);
            GLDS16(sp + 4096, dp + 4096);
        }
        const float e2v = e2p[j * 16 + l15];
        const char* nb = LB + ((j + 1) & 3) * 8192;   // next tile's buffer

        float4v aP[2] = {{0,0,0,0},{0,0,0,0}};
        float4v aQ[2] = {{0,0,0,0},{0,0,0,0}};
        #define KSTEP(ks) \
            aP[0] = __builtin_amdgcn_mfma_f32_16x16x32_bf16(ahf[0][ks], rbh[ks], aP[0], 0, 0, 0); \
            aP[1] = __builtin_amdgcn_mfma_f32_16x16x32_bf16(ahf[1][ks], rbh[ks], aP[1], 0, 0, 0); \
            aP[0] = __builtin_amdgcn_mfma_f32_16x16x32_bf16(alf[0][ks], rbh[ks], aP[0], 0, 0, 0); \
            aP[1] = __builtin_amdgcn_mfma_f32_16x16x32_bf16(alf[1][ks], rbh[ks], aP[1], 0, 0, 0); \
            aQ[0] = __builtin_amdgcn_mfma_f32_16x16x32_bf16(ahf[0][ks], rbl[ks], aQ[0], 0, 0, 0); \
            aQ[1] = __builtin_amdgcn_mfma_f32_16x16x32_bf16(ahf[1][ks], rbl[ks], aQ[1], 0, 0, 0); \
            if (j < 127) { \
                rbh[ks] = *(const short8v*)(nb + fo[ks]); \
                rbl[ks] = *(const short8v*)(nb + 4096 + fo[ks]); \
            }
        KSTEP(0)
        KSTEP(1)
        KSTEP(2)
        KSTEP(3)
        #undef KSTEP

        #pragma unroll
        for (int rt = 0; rt < 2; ++rt) {
            #pragma unroll
            for (int r = 0; r < 4; ++r) {
                float cs = aP[rt][r] + aQ[rt][r];
                float dv = __fmaf_rn(-2.0f, cs, e2v);          // positive (bias)
                unsigned kk = __float_as_uint(dv);
                unsigned mo = m1[rt][r];
                unsigned mx = mo > kk ? mo : kk;
                m2[rt][r] = m2[rt][r] < mx ? m2[rt][r] : mx;
                if (kk < mo) { bk[rt][r] = j; m1[rt][r] = kk; }
            }
        }
        if (j < 124)  asm volatile("s_waitcnt vmcnt(2)" ::: "memory");
        else          asm volatile("s_waitcnt vmcnt(0)" ::: "memory");
        __builtin_amdgcn_s_barrier();
    }

    // exact u64 butterfly over the 16 code-lanes; low bits carry code (tiebreak)
    #pragma unroll
    for (int rt = 0; rt < 2; ++rt) {
        #pragma unroll
        for (int r = 0; r < 4; ++r) {
            unsigned long long key = ((unsigned long long)m1[rt][r] << 32) |
                                     (unsigned)(h * 2048 + bk[rt][r] * 16 + l15);
            unsigned mm2 = m2[rt][r];
            #pragma unroll
            for (int m = 1; m <= 8; m <<= 1) {
                unsigned long long ok = __shfl_xor(key, m, 64);
                unsigned om = __shfl_xor(mm2, m, 64);
                unsigned loser = (ok < key) ? (unsigned)(key >> 32) : (unsigned)(ok >> 32);
                key = ok < key ? ok : key;
                unsigned t2 = om < loser ? om : loser;
                mm2 = mm2 < t2 ? mm2 : t2;
            }
            if (l15 == 0) {
                int tok = d * NTOK + t0 + w * 32 + rt * 16 + lk8 * 4 + r;
                pk[(size_t)h * 65536 + tok] = key;
                pm2[(size_t)h * 65536 + tok] = mm2;
            }
        }
    }
}

// Merge the two code-halves per token: exact u64 first-min + gap flagging.
__global__ __launch_bounds__(256) void merge_kernel(
        const unsigned long long* __restrict__ pk, const unsigned* __restrict__ pm2,
        int* __restrict__ lat, int* __restrict__ flag_cnt, int* __restrict__ flag_list) {
    int tok = blockIdx.x * 256 + threadIdx.x;   // 0..65535 == d*NTOK + t
    unsigned long long ka = pk[tok], kb = pk[65536 + tok];
    unsigned m2a = pm2[tok], m2b = pm2[65536 + tok];
    bool aw = ka < kb;
    unsigned long long kw = aw ? ka : kb;
    unsigned loser1 = (unsigned)((aw ? kb : ka) >> 32);
    unsigned m2w = aw ? m2a : m2b;
    unsigned B2 = m2w < loser1 ? m2w : loser1;
    lat[tok] = (int)(kw & 0xFFFFu);
    float gap = __uint_as_float(B2) - __uint_as_float((unsigned)(kw >> 32));
    if (gap < MARGIN) {
        int slot = atomicAdd(flag_cnt, 1);
        if (slot < FLAG_CAP) flag_list[slot] = tok;
    }
}

// Exact repair, bit-matching verified ref semantics (x2 computed in-kernel).
__global__ __launch_bounds__(256) void repair_kernel(const float* __restrict__ in,
        const float* __restrict__ emb, const float* __restrict__ e2g,
        const int* __restrict__ flag_cnt, const int* __restrict__ flag_list,
        int* __restrict__ lat) {
    __shared__ float xs[ED];
    __shared__ float rd[256];
    __shared__ int   rk[256];
    int n = *flag_cnt;
    if (n > FLAG_CAP) n = FLAG_CAP;
    for (int idx = blockIdx.x; idx < n; idx += gridDim.x) {
        int tok = flag_list[idx];
        int d = tok >> 14;               // tok = d*NTOK + t
        int t = tok & (NTOK - 1);
        __syncthreads();
        if (threadIdx.x < ED) xs[threadIdx.x] = in[(size_t)t * HID + d * ED + threadIdx.x];
        __syncthreads();
        float x2v = 0.f;                 // strict serial, matches ref
        for (int e = 0; e < ED; ++e) x2v = __fadd_rn(x2v, __fmul_rn(xs[e], xs[e]));
        const float* __restrict__ embd = emb + (size_t)d * ED * KCODES;
        float bd = 3.0e38f; int bkk = 0;
        for (int j = 0; j < 16; ++j) {
            int k = threadIdx.x + j * 256;      // ascending k per thread
            float acc = 0.f;
            #pragma unroll 16
            for (int e = 0; e < ED; ++e)
                acc = __fmaf_rn(xs[e], embd[(size_t)e * KCODES + k], acc);
            float dist = __fsub_rn(__fadd_rn(x2v, e2g[d * KCODES + k]),
                                   __fmul_rn(2.0f, acc));
            if (dist < bd) { bd = dist; bkk = k; }
        }
        rd[threadIdx.x] = bd; rk[threadIdx.x] = bkk;
        __syncthreads();
        for (int w = 128; w > 0; w >>= 1) {
            if (threadIdx.x < w) {
                float od = rd[threadIdx.x + w]; int ok = rk[threadIdx.x + w];
                if (od < rd[threadIdx.x] || (od == rd[threadIdx.x] && ok < rk[threadIdx.x])) {
                    rd[threadIdx.x] = od; rk[threadIdx.x] = ok;
                }
            }
            __syncthreads();
        }
        if (threadIdx.x == 0) lat[tok] = rk[0];
    }
}

// out[n] = fl(fl(x + e) - x), n = (d,e,t); per-block partials of (x - e)^2
__global__ __launch_bounds__(256) void gather_kernel(const float* __restrict__ in,
        const float* __restrict__ emb, const int* __restrict__ lat,
        float* __restrict__ out, float* __restrict__ partial) {
    int tid  = threadIdx.x;
    int base = blockIdx.x * 1024 + tid * 4;
    int d = base >> 21;
    int e = (base >> 14) & 127;
    int t = base & (NTOK - 1);
    const int4 kk = *(const int4*)(lat + d * NTOK + t);
    const float* __restrict__ row = emb + ((size_t)(d * ED + e)) * KCODES;
    float enc[4];
    enc[0] = row[kk.x]; enc[1] = row[kk.y]; enc[2] = row[kk.z]; enc[3] = row[kk.w];
    const float4 x = *(const float4*)(in + base);
    const float xv[4] = {x.x, x.y, x.z, x.w};
    float4 ov; float* o = (float*)&ov;
    float s = 0.f;
    #pragma unroll
    for (int i = 0; i < 4; ++i) {
        o[i] = __fsub_rn(__fadd_rn(xv[i], enc[i]), xv[i]);
        float df = xv[i] - enc[i];
        s = __fmaf_rn(df, df, s);
    }
    *(float4*)(out + base) = ov;
    #pragma unroll
    for (int off = 32; off > 0; off >>= 1) s += __shfl_down(s, off, 64);
    __shared__ float wsum[4];
    if ((tid & 63) == 0) wsum[tid >> 6] = s;
    __syncthreads();
    if (tid == 0) partial[blockIdx.x] = wsum[0] + wsum[1] + wsum[2] + wsum[3];
}

__global__ __launch_bounds__(256) void finalize_kernel(const float* __restrict__ partial,
                                                       float* __restrict__ out_tail) {
    __shared__ double sh[256];
    double s = 0.0;
    for (int i = threadIdx.x; i < 8192; i += 256) s += (double)partial[i];
    sh[threadIdx.x] = s;
    __syncthreads();
    for (int w = 128; w > 0; w >>= 1) {
        if (threadIdx.x < w) sh[threadIdx.x] += sh[threadIdx.x + w];
        __syncthreads();
    }
    if (threadIdx.x == 0) {
        double mean = sh[0] / (double)NTOT;
        out_tail[0] = (float)(0.25 * mean);   // loss
        out_tail[1] = (float)mean;            // commit_loss
        ((int*)out_tail)[2] = 0;              // kl (int32 0 == fp32 0.0 bits)
    }
}

extern "C" void kernel_launch(void* const* d_in, const int* in_sizes, int n_in,
                              void* d_out, int out_size, void* d_ws, size_t ws_size,
                              hipStream_t stream) {
    const float* in  = (const float*)d_in[0];
    const float* emb = (const float*)d_in[1];
    float* out = (float*)d_out;
    char* ws = (char*)d_ws;

    int*   lat       = (int*)ws;                          // 256 KB
    float* e2g       = (float*)(ws + 262144);             // 64 KB
    float* partial   = (float*)(ws + 327680);             // 32 KB
    int*   flag_cnt  = (int*)(ws + 360448);               // 4 B
    int*   flag_list = (int*)(ws + 360452);               // 64 KB
    unsigned long long* pk  = (unsigned long long*)(ws + 458752);   // 1 MB
    unsigned*           pm2 = (unsigned*)(ws + 1572864);            // 512 KB
    unsigned short* bfrag = (unsigned short*)(ws + 2097152);        // 8 MB

    hipLaunchKernelGGL(e2split_kernel, dim3(256, 4), dim3(256), 0, stream,
                       emb, e2g, bfrag, flag_cnt);
    hipLaunchKernelGGL(argmin_mfma_kernel, dim3(1024), dim3(256), 0, stream,
                       in, bfrag, e2g, pk, pm2);
    hipLaunchKernelGGL(merge_kernel, dim3(256), dim3(256), 0, stream,
                       pk, pm2, lat, flag_cnt, flag_list);
    hipLaunchKernelGGL(repair_kernel, dim3(64), dim3(256), 0, stream,
                       in, emb, e2g, flag_cnt, flag_list, lat);
    hipLaunchKernelGGL(gather_kernel, dim3(NTOT / 1024), dim3(256), 0, stream,
                       in, emb, lat, out, partial);
    hipLaunchKernelGGL(finalize_kernel, dim3(1), dim3(256), 0, stream, partial, out + NTOT);
}